// Round 2
// baseline (1293.253 us; speedup 1.0000x reference)
//
#include <hip/hip_runtime.h>

typedef unsigned short u16;

#define NQn 100000
#define NAn 200000
#define E1n 250000
#define E2n 250000
#define E3n 500000
#define NLn 100000

__device__ __forceinline__ float bf2f(u16 u) {
    return __uint_as_float(((unsigned)u) << 16);
}
__device__ __forceinline__ u16 f2bf(float f) {
    unsigned x = __float_as_uint(f);
    unsigned r = (x + 0x7fffu + ((x >> 16) & 1u)) >> 16;
    return (u16)r;
}
__device__ __forceinline__ float sigmoidf_(float x) {
    return 1.f / (1.f + __expf(-x));
}

// -------- fold per-relation transforms into K/V weights (fp32 in, bf16 out) --------
// Wbig cols: [0,64): Wq ; [64,128): Wk@A(t0) ; [128,192): Wv@M(t0) ;
//            [192,256): Wk@A(t1) ; [256,320): Wv@M(t1)
__global__ void fold_kernel(
    const float* __restrict__ Wk, const float* __restrict__ Wv, const float* __restrict__ Wq,
    const float* __restrict__ bk, const float* __restrict__ bv, const float* __restrict__ bq,
    const float* __restrict__ a_rel, const float* __restrict__ m_rel,
    int t0, int t1, u16* __restrict__ Wbig, float* __restrict__ bbig, int NOUT)
{
    const int total = 65 * NOUT;   // 64 weight rows + 1 bias row
    for (int idx = blockIdx.x * blockDim.x + threadIdx.x; idx < total;
         idx += gridDim.x * blockDim.x) {
        const int c   = idx / NOUT;
        const int col = idx - c * NOUT;
        const int grp = col >> 6;
        const int oc  = col & 63;
        const int h   = oc >> 5, e = oc & 31;
        if (c < 64) {
            float val;
            if (grp == 0) {
                val = Wq[c * 64 + oc];
            } else {
                const int t = (grp <= 2) ? t0 : t1;
                const float* W = (grp & 1) ? Wk : Wv;
                const float* T = (grp & 1) ? a_rel : m_rel;
                float s = 0.f;
                for (int d = 0; d < 32; ++d)
                    s = fmaf(W[c * 64 + h * 32 + d],
                             T[((t * 2 + h) * 32 + d) * 32 + e], s);
                val = s;
            }
            Wbig[c * NOUT + col] = f2bf(val);
        } else {
            float val;
            if (grp == 0) {
                val = bq[oc];
            } else {
                const int t = (grp <= 2) ? t0 : t1;
                const float* B = (grp & 1) ? bk : bv;
                const float* T = (grp & 1) ? a_rel : m_rel;
                float s = 0.f;
                for (int d = 0; d < 32; ++d)
                    s = fmaf(B[h * 32 + d],
                             T[((t * 2 + h) * 32 + d) * 32 + e], s);
                val = s;
            }
            bbig[col] = val;
        }
    }
}

// -------- fused node projection: h=relu(x@Win+b); big = h@Wbig+bbig --------
template <int NOUT>
__global__ __launch_bounds__(256) void node_kernel(
    const float* __restrict__ x, int N,
    const float* __restrict__ Win, const float* __restrict__ bin,
    const u16* __restrict__ Wbig, const float* __restrict__ bbig,
    u16* __restrict__ h_out, u16* __restrict__ big_out)
{
    constexpr int G = NOUT / 64;
    __shared__ u16 sWin[128 * 64];
    __shared__ u16 sWbig[64 * NOUT];
    __shared__ float sbin[64];
    __shared__ float sbbig[NOUT];
    __shared__ float sX[4][128];
    __shared__ float sH[4][64];

    const int tid = threadIdx.x;
    for (int i = tid; i < 128 * 64; i += 256) sWin[i] = f2bf(Win[i]);
    for (int i = tid; i < 64 * NOUT; i += 256) sWbig[i] = Wbig[i];
    if (tid < 64) sbin[tid] = bin[tid];
    for (int i = tid; i < NOUT; i += 256) sbbig[i] = bbig[i];
    __syncthreads();

    const int nl = tid >> 6;
    const int oc = tid & 63;
    const int ntiles = (N + 3) >> 2;
    for (int tile = blockIdx.x; tile < ntiles; tile += gridDim.x) {
        const int node = tile * 4 + nl;
        const bool valid = node < N;
        if (valid) {
            sX[nl][oc]      = x[(size_t)node * 128 + oc];
            sX[nl][oc + 64] = x[(size_t)node * 128 + 64 + oc];
        }
        __syncthreads();
        float h = 0.f;
        if (valid) {
            float acc = sbin[oc];
            #pragma unroll 8
            for (int i = 0; i < 128; ++i)
                acc = fmaf(sX[nl][i], bf2f(sWin[i * 64 + oc]), acc);
            h = fmaxf(acc, 0.f);
            h_out[(size_t)node * 64 + oc] = f2bf(h);
        }
        sH[nl][oc] = h;
        __syncthreads();
        if (valid) {
            float acc2[G];
            #pragma unroll
            for (int j = 0; j < G; ++j) acc2[j] = sbbig[j * 64 + oc];
            #pragma unroll 4
            for (int c = 0; c < 64; ++c) {
                const float hv = sH[nl][c];
                #pragma unroll
                for (int j = 0; j < G; ++j)
                    acc2[j] = fmaf(hv, bf2f(sWbig[c * NOUT + j * 64 + oc]), acc2[j]);
            }
            #pragma unroll
            for (int j = 0; j < G; ++j)
                big_out[(size_t)node * NOUT + j * 64 + oc] = f2bf(acc2[j]);
        }
        __syncthreads();
    }
}

// -------- edge pass: score, exp, atomic accumulate (no max-sub needed) -----
__global__ __launch_bounds__(256) void edge_kernel(
    const int* __restrict__ src, const int* __restrict__ dst, int E,
    const u16* __restrict__ srcArr, int srcStride, int kOff, int vOff,
    const u16* __restrict__ dstQ, int dstStride,
    const float* __restrict__ w, const float* __restrict__ p_rel, int t,
    float* __restrict__ accum, float* __restrict__ denom)
{
    const int gid = blockIdx.x * 256 + threadIdx.x;
    const int e = gid >> 6;          // one wave per edge
    if (e >= E) return;
    const int lane = threadIdx.x & 63;
    const int h = lane >> 5;
    const int s = src[e];
    const int d = dst[e];
    const float qv = bf2f(dstQ[(size_t)d * dstStride + lane]);
    const float kv = bf2f(srcArr[(size_t)s * srcStride + kOff + lane]);
    float p = qv * kv;
    p += __shfl_xor(p, 16);          // masks <32 stay within each head-half
    p += __shfl_xor(p, 8);
    p += __shfl_xor(p, 4);
    p += __shfl_xor(p, 2);
    p += __shfl_xor(p, 1);
    const float pr = p_rel[t * 2 + h] * 0.17677669529663687f; // 1/sqrt(32)
    const float ex = __expf(p * pr);
    const float wv = w[e];
    const float vv = bf2f(srcArr[(size_t)s * srcStride + vOff + lane]);
    atomicAdd(&accum[(size_t)d * 64 + lane], ex * wv * vv);
    if ((lane & 31) == 0) atomicAdd(&denom[d * 2 + h], ex);
}

// -------- finalize: gelu(accum/denom) @ Wo + bo, gated skip ----------------
__global__ __launch_bounds__(256) void finalize_kernel(
    const float* __restrict__ accum, const float* __restrict__ denom,
    const u16* __restrict__ h_in,
    const float* __restrict__ Wo, const float* __restrict__ bo,
    const float* __restrict__ skip, u16* __restrict__ z_out, int N)
{
    __shared__ float sWo[64 * 64];
    __shared__ float sbo[64];
    __shared__ float sG[4][64];
    for (int i = threadIdx.x; i < 4096; i += 256) sWo[i] = Wo[i];
    if (threadIdx.x < 64) sbo[threadIdx.x] = bo[threadIdx.x];
    __syncthreads();
    const float sk = sigmoidf_(skip[0]);
    const int nl = threadIdx.x >> 6, oc = threadIdx.x & 63, h = oc >> 5;
    const int ntiles = (N + 3) >> 2;
    for (int tile = blockIdx.x; tile < ntiles; tile += gridDim.x) {
        const int node = tile * 4 + nl;
        const bool valid = node < N;
        float g = 0.f;
        if (valid) {
            const float a = accum[(size_t)node * 64 + oc];
            const float dn = denom[node * 2 + h] + 1e-16f;
            const float xx = a / dn;
            // gelu tanh approximation (jax default approximate=True)
            const float u = 0.7978845608028654f * (xx + 0.044715f * xx * xx * xx);
            const float th = 1.f - 2.f / (__expf(2.f * u) + 1.f);
            g = 0.5f * xx * (1.f + th);
        }
        sG[nl][oc] = g;
        __syncthreads();
        if (valid) {
            float acc = sbo[oc];
            #pragma unroll 4
            for (int c = 0; c < 64; ++c)
                acc = fmaf(sG[nl][c], sWo[c * 64 + oc], acc);
            const float hv = bf2f(h_in[(size_t)node * 64 + oc]);
            z_out[(size_t)node * 64 + oc] = f2bf(sk * acc + (1.f - sk) * hv);
        }
        __syncthreads();
    }
}

// -------- decoder: sigmoid(dot64) link prediction --------------------------
__global__ __launch_bounds__(256) void decoder_kernel(
    const u16* __restrict__ z_q, const u16* __restrict__ z_a,
    const int* __restrict__ pos_idx, const int* __restrict__ neg_idx,
    float* __restrict__ out)
{
    const int gid = blockIdx.x * 256 + threadIdx.x;
    const int o = gid >> 5;         // half-wave per output
    if (o >= 2 * NLn) return;
    const int lane = threadIdx.x & 31;
    const int* idx;
    int i;
    if (o < NLn) { idx = pos_idx; i = o; }
    else         { idx = neg_idx; i = o - NLn; }
    const int r0 = idx[i];
    const int r1 = idx[NLn + i];
    float s = bf2f(z_q[(size_t)r0 * 64 + 2 * lane])     * bf2f(z_a[(size_t)r1 * 64 + 2 * lane])
            + bf2f(z_q[(size_t)r0 * 64 + 2 * lane + 1]) * bf2f(z_a[(size_t)r1 * 64 + 2 * lane + 1]);
    s += __shfl_xor(s, 16);
    s += __shfl_xor(s, 8);
    s += __shfl_xor(s, 4);
    s += __shfl_xor(s, 2);
    s += __shfl_xor(s, 1);
    if (lane == 0) out[o] = sigmoidf_(s);
}

extern "C" void kernel_launch(void* const* d_in, const int* in_sizes, int n_in,
                              void* d_out, int out_size, void* d_ws, size_t ws_size,
                              hipStream_t stream)
{
    (void)in_sizes; (void)n_in; (void)out_size;
    const float* x_q   = (const float*)d_in[0];
    const float* x_a   = (const float*)d_in[1];
    const int* ei_qca  = (const int*)d_in[2];
    const int* ei_qwa  = (const int*)d_in[3];
    const int* ei_rev  = (const int*)d_in[4];
    const int* pos_idx = (const int*)d_in[5];
    const int* neg_idx = (const int*)d_in[6];
    const float* w_qca = (const float*)d_in[7];
    const float* w_qwa = (const float*)d_in[8];
    const float* w_rev = (const float*)d_in[9];
    const float* W_in_q = (const float*)d_in[10]; const float* b_in_q = (const float*)d_in[11];
    const float* W_in_a = (const float*)d_in[12]; const float* b_in_a = (const float*)d_in[13];
    const float* Wk_qn = (const float*)d_in[14], *bk_qn = (const float*)d_in[15];
    const float* Wq_qn = (const float*)d_in[16], *bq_qn = (const float*)d_in[17];
    const float* Wv_qn = (const float*)d_in[18], *bv_qn = (const float*)d_in[19];
    const float* Wk_an = (const float*)d_in[20], *bk_an = (const float*)d_in[21];
    const float* Wq_an = (const float*)d_in[22], *bq_an = (const float*)d_in[23];
    const float* Wv_an = (const float*)d_in[24], *bv_an = (const float*)d_in[25];
    const float* a_rel = (const float*)d_in[26];
    const float* m_rel = (const float*)d_in[27];
    const float* p_rel = (const float*)d_in[28];
    const float* Wo_qn = (const float*)d_in[29], *bo_qn = (const float*)d_in[30];
    const float* Wo_an = (const float*)d_in[31], *bo_an = (const float*)d_in[32];
    const float* skip_qn = (const float*)d_in[33], *skip_an = (const float*)d_in[34];

    char* ws = (char*)d_ws;
    size_t off = 0;
    auto alloc = [&](size_t bytes) -> char* {
        char* p = ws + off;
        off = (off + bytes + 255) & ~(size_t)255;
        return p;
    };
    u16* big_q = (u16*)alloc((size_t)NQn * 320 * 2);  // q | k0 | v0 | k1 | v1
    u16* big_a = (u16*)alloc((size_t)NAn * 192 * 2);  // q | k2 | v2
    u16* h_q   = (u16*)alloc((size_t)NQn * 64 * 2);
    u16* h_a   = (u16*)alloc((size_t)NAn * 64 * 2);
    char* zero_start = ws + off;
    float* accum_a = (float*)alloc((size_t)NAn * 64 * 4);
    float* accum_q = (float*)alloc((size_t)NQn * 64 * 4);
    float* denom_a = (float*)alloc((size_t)NAn * 2 * 4);
    float* denom_q = (float*)alloc((size_t)NQn * 2 * 4);
    char* zero_end = ws + off;
    u16* z_q = (u16*)alloc((size_t)NQn * 64 * 2);
    u16* z_a = (u16*)alloc((size_t)NAn * 64 * 2);
    u16* Wbig_q = (u16*)alloc(64 * 320 * 2);
    float* bbig_q = (float*)alloc(320 * 4);
    u16* Wbig_a = (u16*)alloc(64 * 192 * 2);
    float* bbig_a = (float*)alloc(192 * 4);

    if (off > ws_size) return;  // workspace too small: leave output zeroed (visible failure)

    hipMemsetAsync(zero_start, 0, (size_t)(zero_end - zero_start), stream);

    fold_kernel<<<64, 256, 0, stream>>>(Wk_qn, Wv_qn, Wq_qn, bk_qn, bv_qn, bq_qn,
                                        a_rel, m_rel, 0, 1, Wbig_q, bbig_q, 320);
    fold_kernel<<<64, 256, 0, stream>>>(Wk_an, Wv_an, Wq_an, bk_an, bv_an, bq_an,
                                        a_rel, m_rel, 2, -1, Wbig_a, bbig_a, 192);

    node_kernel<320><<<2048, 256, 0, stream>>>(x_q, NQn, W_in_q, b_in_q, Wbig_q, bbig_q, h_q, big_q);
    node_kernel<192><<<2048, 256, 0, stream>>>(x_a, NAn, W_in_a, b_in_a, Wbig_a, bbig_a, h_a, big_a);

    edge_kernel<<<(E1n * 64 + 255) / 256, 256, 0, stream>>>(
        ei_qca, ei_qca + E1n, E1n, big_q, 320, 64, 128, big_a, 192, w_qca, p_rel, 0, accum_a, denom_a);
    edge_kernel<<<(E2n * 64 + 255) / 256, 256, 0, stream>>>(
        ei_qwa, ei_qwa + E2n, E2n, big_q, 320, 192, 256, big_a, 192, w_qwa, p_rel, 1, accum_a, denom_a);
    edge_kernel<<<(E3n * 64 + 255) / 256, 256, 0, stream>>>(
        ei_rev, ei_rev + E3n, E3n, big_a, 192, 64, 128, big_q, 320, w_rev, p_rel, 2, accum_q, denom_q);

    finalize_kernel<<<2048, 256, 0, stream>>>(accum_a, denom_a, h_a, Wo_an, bo_an, skip_an, z_a, NAn);
    finalize_kernel<<<2048, 256, 0, stream>>>(accum_q, denom_q, h_q, Wo_qn, bo_qn, skip_qn, z_q, NQn);

    decoder_kernel<<<(2 * NLn * 32 + 255) / 256, 256, 0, stream>>>(
        z_q, z_a, pos_idx, neg_idx, (float*)d_out);
}

// Round 3
// 812.243 us; speedup vs baseline: 1.5922x; 1.5922x over previous
//
#include <hip/hip_runtime.h>

typedef unsigned short u16;
typedef __attribute__((ext_vector_type(8))) short short8;   // 8 bf16 = 4 VGPRs
typedef __attribute__((ext_vector_type(4))) float f32x4;

#define NQn 100000
#define NAn 200000
#define E1n 250000
#define E2n 250000
#define E3n 500000
#define NLn 100000

__device__ __forceinline__ float bf2f(u16 u) {
    return __uint_as_float(((unsigned)u) << 16);
}
__device__ __forceinline__ u16 f2bf(float f) {
    unsigned x = __float_as_uint(f);
    unsigned r = (x + 0x7fffu + ((x >> 16) & 1u)) >> 16;
    return (u16)r;
}
__device__ __forceinline__ float sigmoidf_(float x) {
    return 1.f / (1.f + __expf(-x));
}

// -------- fold per-relation transforms into K/V weights (fp32 in, bf16 out) --------
// Wbig cols: [0,64): Wq ; [64,128): Wk@A(t0) ; [128,192): Wv@M(t0) ;
//            [192,256): Wk@A(t1) ; [256,320): Wv@M(t1)
__global__ void fold_kernel(
    const float* __restrict__ Wk, const float* __restrict__ Wv, const float* __restrict__ Wq,
    const float* __restrict__ bk, const float* __restrict__ bv, const float* __restrict__ bq,
    const float* __restrict__ a_rel, const float* __restrict__ m_rel,
    int t0, int t1, u16* __restrict__ Wbig, float* __restrict__ bbig, int NOUT)
{
    const int total = 65 * NOUT;   // 64 weight rows + 1 bias row
    for (int idx = blockIdx.x * blockDim.x + threadIdx.x; idx < total;
         idx += gridDim.x * blockDim.x) {
        const int c   = idx / NOUT;
        const int col = idx - c * NOUT;
        const int grp = col >> 6;
        const int oc  = col & 63;
        const int h   = oc >> 5, e = oc & 31;
        if (c < 64) {
            float val;
            if (grp == 0) {
                val = Wq[c * 64 + oc];
            } else {
                const int t = (grp <= 2) ? t0 : t1;
                const float* W = (grp & 1) ? Wk : Wv;
                const float* T = (grp & 1) ? a_rel : m_rel;
                float s = 0.f;
                for (int d = 0; d < 32; ++d)
                    s = fmaf(W[c * 64 + h * 32 + d],
                             T[((t * 2 + h) * 32 + d) * 32 + e], s);
                val = s;
            }
            Wbig[c * NOUT + col] = f2bf(val);
        } else {
            float val;
            if (grp == 0) {
                val = bq[oc];
            } else {
                const int t = (grp <= 2) ? t0 : t1;
                const float* B = (grp & 1) ? bk : bv;
                const float* T = (grp & 1) ? a_rel : m_rel;
                float s = 0.f;
                for (int d = 0; d < 32; ++d)
                    s = fmaf(B[h * 32 + d],
                             T[((t * 2 + h) * 32 + d) * 32 + e], s);
                val = s;
            }
            bbig[col] = val;
        }
    }
}

// -------- MFMA fused node projection --------------------------------------
// Stage 1: h[16x64] = relu(x[16x128] @ Win[128x64] + b1)   (per wave)
// Stage 2: big[16xNOUT] = h[16x64] @ Wbig[64xNOUT] + b2
// MFMA 16x16x32 bf16 layouts (m89/m91-verified):
//   A: a[m = lane&15][k = (lane>>4)*8 + j]  (8 contiguous-k bf16 per lane)
//   B: b[k = (lane>>4)*8 + j][n = lane&15]
//   D: d[row = (lane>>4)*4 + r][col = lane&15]
template <int NOUT>
__global__ __launch_bounds__(256, 2) void node_mfma(
    const float* __restrict__ x, int N,
    const float* __restrict__ Win, const float* __restrict__ bin,
    const u16* __restrict__ Wbig, const float* __restrict__ bbig,
    u16* __restrict__ h_out, u16* __restrict__ big_out)
{
    constexpr int NT = NOUT / 16;            // stage-2 col tiles
    __shared__ __align__(16) short sB1[4 * 4 * 64 * 8];   // [kt][nt][lane][j], 16 KB
    __shared__ __align__(16) short sB2[2 * NT * 64 * 8];  // [kt2][nt][lane][j]
    __shared__ __align__(16) short sH[4][16 * 72];        // per-wave h tile, stride 72
    __shared__ float sb1[64];
    __shared__ float sb2[NOUT];

    const int tid = threadIdx.x;
    // stage-1 weights -> fragment-swizzled bf16 LDS
    for (int idx = tid; idx < 4 * 4 * 64 * 8; idx += 256) {
        const int j = idx & 7;
        const int ln = (idx >> 3) & 63;
        const int f = idx >> 9;              // kt*4 + nt
        const int kt = f >> 2, nt = f & 3;
        const int k = kt * 32 + (ln >> 4) * 8 + j;
        const int n = nt * 16 + (ln & 15);
        sB1[idx] = (short)f2bf(Win[k * 64 + n]);
    }
    // stage-2 weights (already bf16) -> fragment-swizzled LDS
    for (int idx = tid; idx < 2 * NT * 64 * 8; idx += 256) {
        const int j = idx & 7;
        const int ln = (idx >> 3) & 63;
        const int f = idx >> 9;              // kt2*NT + nt
        const int kt2 = f / NT, nt = f - kt2 * NT;
        const int k = kt2 * 32 + (ln >> 4) * 8 + j;
        const int n = nt * 16 + (ln & 15);
        sB2[idx] = (short)Wbig[k * NOUT + n];
    }
    if (tid < 64) sb1[tid] = bin[tid];
    for (int i = tid; i < NOUT; i += 256) sb2[i] = bbig[i];
    __syncthreads();

    const int wave = tid >> 6;
    const int lane = tid & 63;
    const int quad = lane >> 4;
    const int mrow = lane & 15;
    short* const myH = &sH[wave][0];

    const int ntiles = (N + 63) >> 6;
    for (int tile = blockIdx.x; tile < ntiles; tile += gridDim.x) {
        const int nbase = tile * 64 + wave * 16;
        const int node = nbase + mrow;

        // ---- stage 1: A fragments from global fp32 x ----
        short8 a1[4];
        if (node < N) {
            const float* xp = x + (size_t)node * 128 + quad * 8;
            #pragma unroll
            for (int kt = 0; kt < 4; ++kt) {
                const float4 u0 = *(const float4*)(xp + kt * 32);
                const float4 u1 = *(const float4*)(xp + kt * 32 + 4);
                short8 f;
                f[0] = (short)f2bf(u0.x); f[1] = (short)f2bf(u0.y);
                f[2] = (short)f2bf(u0.z); f[3] = (short)f2bf(u0.w);
                f[4] = (short)f2bf(u1.x); f[5] = (short)f2bf(u1.y);
                f[6] = (short)f2bf(u1.z); f[7] = (short)f2bf(u1.w);
                a1[kt] = f;
            }
        } else {
            #pragma unroll
            for (int kt = 0; kt < 4; ++kt) a1[kt] = short8{0,0,0,0,0,0,0,0};
        }

        #pragma unroll
        for (int nt = 0; nt < 4; ++nt) {
            const float bv = sb1[nt * 16 + mrow];
            f32x4 acc = {bv, bv, bv, bv};
            #pragma unroll
            for (int kt = 0; kt < 4; ++kt) {
                const short8 bf = *(const short8*)&sB1[((kt * 4 + nt) * 64 + lane) * 8];
                acc = __builtin_amdgcn_mfma_f32_16x16x32_bf16(a1[kt], bf, acc, 0, 0, 0);
            }
            // relu, write h to global + wave-private LDS tile (C->A relayout)
            #pragma unroll
            for (int r = 0; r < 4; ++r) {
                const int row = quad * 4 + r;
                const int nd = nbase + row;
                const u16 hb = f2bf(fmaxf(acc[r], 0.f));
                myH[row * 72 + nt * 16 + mrow] = (short)hb;
                if (nd < N) h_out[(size_t)nd * 64 + nt * 16 + mrow] = hb;
            }
        }

        // ---- stage 2: A fragments from wave-private LDS h tile ----
        short8 a2[2];
        #pragma unroll
        for (int kt2 = 0; kt2 < 2; ++kt2)
            a2[kt2] = *(const short8*)&myH[mrow * 72 + kt2 * 32 + quad * 8];

        for (int nt = 0; nt < NT; ++nt) {
            const float bv = sb2[nt * 16 + mrow];
            f32x4 acc = {bv, bv, bv, bv};
            const short8 b0 = *(const short8*)&sB2[((0 * NT + nt) * 64 + lane) * 8];
            acc = __builtin_amdgcn_mfma_f32_16x16x32_bf16(a2[0], b0, acc, 0, 0, 0);
            const short8 b1 = *(const short8*)&sB2[((1 * NT + nt) * 64 + lane) * 8];
            acc = __builtin_amdgcn_mfma_f32_16x16x32_bf16(a2[1], b1, acc, 0, 0, 0);
            #pragma unroll
            for (int r = 0; r < 4; ++r) {
                const int nd = nbase + quad * 4 + r;
                if (nd < N)
                    big_out[(size_t)nd * NOUT + nt * 16 + mrow] = f2bf(acc[r]);
            }
        }
    }
}

// -------- edge pass: score, exp, atomic accumulate (no max-sub needed) -----
__global__ __launch_bounds__(256) void edge_kernel(
    const int* __restrict__ src, const int* __restrict__ dst, int E,
    const u16* __restrict__ srcArr, int srcStride, int kOff, int vOff,
    const u16* __restrict__ dstQ, int dstStride,
    const float* __restrict__ w, const float* __restrict__ p_rel, int t,
    float* __restrict__ accum, float* __restrict__ denom)
{
    const int gid = blockIdx.x * 256 + threadIdx.x;
    const int e = gid >> 6;          // one wave per edge
    if (e >= E) return;
    const int lane = threadIdx.x & 63;
    const int h = lane >> 5;
    const int s = src[e];
    const int d = dst[e];
    const float qv = bf2f(dstQ[(size_t)d * dstStride + lane]);
    const float kv = bf2f(srcArr[(size_t)s * srcStride + kOff + lane]);
    float p = qv * kv;
    p += __shfl_xor(p, 16);          // masks <32 stay within each head-half
    p += __shfl_xor(p, 8);
    p += __shfl_xor(p, 4);
    p += __shfl_xor(p, 2);
    p += __shfl_xor(p, 1);
    const float pr = p_rel[t * 2 + h] * 0.17677669529663687f; // 1/sqrt(32)
    const float ex = __expf(p * pr);
    const float wv = w[e];
    const float vv = bf2f(srcArr[(size_t)s * srcStride + vOff + lane]);
    atomicAdd(&accum[(size_t)d * 64 + lane], ex * wv * vv);
    if ((lane & 31) == 0) atomicAdd(&denom[d * 2 + h], ex);
}

// -------- finalize: gelu(accum/denom) @ Wo + bo, gated skip ----------------
__global__ __launch_bounds__(256) void finalize_kernel(
    const float* __restrict__ accum, const float* __restrict__ denom,
    const u16* __restrict__ h_in,
    const float* __restrict__ Wo, const float* __restrict__ bo,
    const float* __restrict__ skip, u16* __restrict__ z_out, int N)
{
    __shared__ float sWo[64 * 64];
    __shared__ float sbo[64];
    __shared__ float sG[4][64];
    for (int i = threadIdx.x; i < 4096; i += 256) sWo[i] = Wo[i];
    if (threadIdx.x < 64) sbo[threadIdx.x] = bo[threadIdx.x];
    __syncthreads();
    const float sk = sigmoidf_(skip[0]);
    const int nl = threadIdx.x >> 6, oc = threadIdx.x & 63, h = oc >> 5;
    const int ntiles = (N + 3) >> 2;
    for (int tile = blockIdx.x; tile < ntiles; tile += gridDim.x) {
        const int node = tile * 4 + nl;
        const bool valid = node < N;
        float g = 0.f;
        if (valid) {
            const float a = accum[(size_t)node * 64 + oc];
            const float dn = denom[node * 2 + h] + 1e-16f;
            const float xx = a / dn;
            // gelu tanh approximation (jax default approximate=True)
            const float u = 0.7978845608028654f * (xx + 0.044715f * xx * xx * xx);
            const float th = 1.f - 2.f / (__expf(2.f * u) + 1.f);
            g = 0.5f * xx * (1.f + th);
        }
        sG[nl][oc] = g;
        __syncthreads();
        if (valid) {
            float acc = sbo[oc];
            #pragma unroll 4
            for (int c = 0; c < 64; ++c)
                acc = fmaf(sG[nl][c], sWo[c * 64 + oc], acc);
            const float hv = bf2f(h_in[(size_t)node * 64 + oc]);
            z_out[(size_t)node * 64 + oc] = f2bf(sk * acc + (1.f - sk) * hv);
        }
        __syncthreads();
    }
}

// -------- decoder: sigmoid(dot64) link prediction --------------------------
__global__ __launch_bounds__(256) void decoder_kernel(
    const u16* __restrict__ z_q, const u16* __restrict__ z_a,
    const int* __restrict__ pos_idx, const int* __restrict__ neg_idx,
    float* __restrict__ out)
{
    const int gid = blockIdx.x * 256 + threadIdx.x;
    const int o = gid >> 5;         // half-wave per output
    if (o >= 2 * NLn) return;
    const int lane = threadIdx.x & 31;
    const int* idx;
    int i;
    if (o < NLn) { idx = pos_idx; i = o; }
    else         { idx = neg_idx; i = o - NLn; }
    const int r0 = idx[i];
    const int r1 = idx[NLn + i];
    float s = bf2f(z_q[(size_t)r0 * 64 + 2 * lane])     * bf2f(z_a[(size_t)r1 * 64 + 2 * lane])
            + bf2f(z_q[(size_t)r0 * 64 + 2 * lane + 1]) * bf2f(z_a[(size_t)r1 * 64 + 2 * lane + 1]);
    s += __shfl_xor(s, 16);
    s += __shfl_xor(s, 8);
    s += __shfl_xor(s, 4);
    s += __shfl_xor(s, 2);
    s += __shfl_xor(s, 1);
    if (lane == 0) out[o] = sigmoidf_(s);
}

extern "C" void kernel_launch(void* const* d_in, const int* in_sizes, int n_in,
                              void* d_out, int out_size, void* d_ws, size_t ws_size,
                              hipStream_t stream)
{
    (void)in_sizes; (void)n_in; (void)out_size;
    const float* x_q   = (const float*)d_in[0];
    const float* x_a   = (const float*)d_in[1];
    const int* ei_qca  = (const int*)d_in[2];
    const int* ei_qwa  = (const int*)d_in[3];
    const int* ei_rev  = (const int*)d_in[4];
    const int* pos_idx = (const int*)d_in[5];
    const int* neg_idx = (const int*)d_in[6];
    const float* w_qca = (const float*)d_in[7];
    const float* w_qwa = (const float*)d_in[8];
    const float* w_rev = (const float*)d_in[9];
    const float* W_in_q = (const float*)d_in[10]; const float* b_in_q = (const float*)d_in[11];
    const float* W_in_a = (const float*)d_in[12]; const float* b_in_a = (const float*)d_in[13];
    const float* Wk_qn = (const float*)d_in[14], *bk_qn = (const float*)d_in[15];
    const float* Wq_qn = (const float*)d_in[16], *bq_qn = (const float*)d_in[17];
    const float* Wv_qn = (const float*)d_in[18], *bv_qn = (const float*)d_in[19];
    const float* Wk_an = (const float*)d_in[20], *bk_an = (const float*)d_in[21];
    const float* Wq_an = (const float*)d_in[22], *bq_an = (const float*)d_in[23];
    const float* Wv_an = (const float*)d_in[24], *bv_an = (const float*)d_in[25];
    const float* a_rel = (const float*)d_in[26];
    const float* m_rel = (const float*)d_in[27];
    const float* p_rel = (const float*)d_in[28];
    const float* Wo_qn = (const float*)d_in[29], *bo_qn = (const float*)d_in[30];
    const float* Wo_an = (const float*)d_in[31], *bo_an = (const float*)d_in[32];
    const float* skip_qn = (const float*)d_in[33], *skip_an = (const float*)d_in[34];

    char* ws = (char*)d_ws;
    size_t off = 0;
    auto alloc = [&](size_t bytes) -> char* {
        char* p = ws + off;
        off = (off + bytes + 255) & ~(size_t)255;
        return p;
    };
    u16* big_q = (u16*)alloc((size_t)NQn * 320 * 2);  // q | k0 | v0 | k1 | v1
    u16* big_a = (u16*)alloc((size_t)NAn * 192 * 2);  // q | k2 | v2
    u16* h_q   = (u16*)alloc((size_t)NQn * 64 * 2);
    u16* h_a   = (u16*)alloc((size_t)NAn * 64 * 2);
    char* zero_start = ws + off;
    float* accum_a = (float*)alloc((size_t)NAn * 64 * 4);
    float* accum_q = (float*)alloc((size_t)NQn * 64 * 4);
    float* denom_a = (float*)alloc((size_t)NAn * 2 * 4);
    float* denom_q = (float*)alloc((size_t)NQn * 2 * 4);
    char* zero_end = ws + off;
    u16* z_q = (u16*)alloc((size_t)NQn * 64 * 2);
    u16* z_a = (u16*)alloc((size_t)NAn * 64 * 2);
    u16* Wbig_q = (u16*)alloc(64 * 320 * 2);
    float* bbig_q = (float*)alloc(320 * 4);
    u16* Wbig_a = (u16*)alloc(64 * 192 * 2);
    float* bbig_a = (float*)alloc(192 * 4);

    if (off > ws_size) return;  // workspace too small: leave output zeroed (visible failure)

    hipMemsetAsync(zero_start, 0, (size_t)(zero_end - zero_start), stream);

    fold_kernel<<<64, 256, 0, stream>>>(Wk_qn, Wv_qn, Wq_qn, bk_qn, bv_qn, bq_qn,
                                        a_rel, m_rel, 0, 1, Wbig_q, bbig_q, 320);
    fold_kernel<<<64, 256, 0, stream>>>(Wk_an, Wv_an, Wq_an, bk_an, bv_an, bq_an,
                                        a_rel, m_rel, 2, -1, Wbig_a, bbig_a, 192);

    node_mfma<320><<<512, 256, 0, stream>>>(x_q, NQn, W_in_q, b_in_q, Wbig_q, bbig_q, h_q, big_q);
    node_mfma<192><<<512, 256, 0, stream>>>(x_a, NAn, W_in_a, b_in_a, Wbig_a, bbig_a, h_a, big_a);

    edge_kernel<<<(E1n * 64 + 255) / 256, 256, 0, stream>>>(
        ei_qca, ei_qca + E1n, E1n, big_q, 320, 64, 128, big_a, 192, w_qca, p_rel, 0, accum_a, denom_a);
    edge_kernel<<<(E2n * 64 + 255) / 256, 256, 0, stream>>>(
        ei_qwa, ei_qwa + E2n, E2n, big_q, 320, 192, 256, big_a, 192, w_qwa, p_rel, 1, accum_a, denom_a);
    edge_kernel<<<(E3n * 64 + 255) / 256, 256, 0, stream>>>(
        ei_rev, ei_rev + E3n, E3n, big_a, 192, 64, 128, big_q, 320, w_rev, p_rel, 2, accum_q, denom_q);

    finalize_kernel<<<2048, 256, 0, stream>>>(accum_a, denom_a, h_a, Wo_an, bo_an, skip_an, z_a, NAn);
    finalize_kernel<<<2048, 256, 0, stream>>>(accum_q, denom_q, h_q, Wo_qn, bo_qn, skip_qn, z_q, NQn);

    decoder_kernel<<<(2 * NLn * 32 + 255) / 256, 256, 0, stream>>>(
        z_q, z_a, pos_idx, neg_idx, (float*)d_out);
}